// Round 8
// baseline (126.985 us; speedup 1.0000x reference)
//
#include <hip/hip_runtime.h>

// Problem constants
#define Bz 16      // batch
#define Tin 12     // T_IN
#define Ttot 24    // T_TOTAL
#define NN 5000    // nodes
#define KK 16      // neighbors
#define HH 4       // heads
#define OO 12      // T_TOTAL - T_IN
#define TH 48      // Tin * HH
#define G  8       // bt-groups (2 batches each) == number of XCDs
#define JJ 24      // (b,t) pairs per group

// Native clang vectors (HIP float4 is a class type the builtins reject).
typedef float nfloat4 __attribute__((ext_vector_type(4)));
typedef float f2 __attribute__((ext_vector_type(2)));   // packed-math pairs

__device__ __forceinline__ float4 nt_load4(const float4* p) {
    nfloat4 v = __builtin_nontemporal_load((const nfloat4*)p);
    return *(float4*)&v;
}
__device__ __forceinline__ void nt_store4(float4 v, float4* p) {
    __builtin_nontemporal_store(*(nfloat4*)&v, (nfloat4*)p);
}

// ============ kernel 1: transpose x -> xT2(g, N, 24) + concat copy ==========
#define K1_NB 64   // nodes per tile
#define K1_BT 24   // (b,t) pairs per tile == JJ
#define K1_TILES 79   // ceil(5000/64)

__global__ __launch_bounds__(256) void transpose_concat_kernel(
    const float4* __restrict__ x4,   // (BT, N)
    float4* __restrict__ xT2,        // (G, N, JJ)
    float4* __restrict__ out4,       // (B*Ttot, N)
    int* __restrict__ k2ctr)         // 8 ints, consumed by kernel 2
{
    __shared__ float4 tile[K1_BT][K1_NB + 1];
    const int bid = blockIdx.x;
    const int g   = bid & 7;
    const int n0  = (bid >> 3) * K1_NB;
    const int bt0 = g * K1_BT;
    const int rem = min(K1_NB, NN - n0);
    const int tid = threadIdx.x;

    // zero kernel-2's work counters (ws poison scrambles them every iteration;
    // k1 completes before k2 launches -> stream-order visibility)
    if (bid == 0 && tid < G) k2ctr[tid] = 0;

    #pragma unroll
    for (int r = 0; r < (K1_NB * K1_BT) / 256; r++) {
        int tau = r * 256 + tid;
        int j = tau / K1_NB;
        int i = tau % K1_NB;
        if (i < rem) {
            int bt = bt0 + j;
            float4 v = nt_load4(&x4[(size_t)bt * NN + n0 + i]);
            tile[j][i] = v;
            int b = bt / Tin, t = bt - b * Tin;
            nt_store4(v, &out4[(size_t)(b * Ttot + t) * NN + n0 + i]);
        }
    }
    __syncthreads();

    // xT2 IS re-read by kernel 2 -> regular (allocating) store.
    #pragma unroll
    for (int r = 0; r < (K1_NB * K1_BT) / 256; r++) {
        int tau = r * 256 + tid;
        int i = tau / K1_BT;
        int j = tau - i * K1_BT;
        if (i < rem) {
            xT2[((size_t)g * NN + (n0 + i)) * JJ + j] = tile[j][i];
        }
    }
}

// ============ kernel 2: XCD-self-assigned gather + aggregate + GEMM =========
// Each block reads its REAL XCD id (s_getreg HW_REG_XCC_ID) and pops work for
// group g == its own XCD -> each XCD's L2 only holds its 1.92 MB slice, so the
// 245 MB of gather re-reads are local-L2 hits regardless of dispatch mapping.
#define NPB 8                  // nodes per chunk
#define CPB 5                  // chunks per block (pop granularity: 40 nodes)
#define CAP 125                // macro-chunks per group; 8*125 = 1000 = grid
// Compact feat layout (float4 units): L = nl*FSN2 + b_l*FSB2 + h*12 + t
#define FSB2 49
#define FSN2 99                // 2*49 + 1
#define WTS  52                // Wt_s row stride in floats

__global__ __launch_bounds__(192) void gnn_main_kernel(
    const float4* __restrict__ xT2,   // (G, N, JJ)
    const float* __restrict__ dists,  // (N, K)
    const float* __restrict__ W,      // (48, 12)
    const float* __restrict__ bias,   // (12,)
    const int*   __restrict__ nbrs,   // (N, K)
    float4* __restrict__ out4,        // (B*Ttot, N)
    int* __restrict__ ctr)            // 8 work counters (zeroed by k1)
{
    __shared__ float4 feat[NPB * FSN2];     // 12.4 KB
    __shared__ float4 w4_s[NPB][KK + 1];
    __shared__ float  Wt_s[OO * WTS];
    __shared__ float  bias_s[OO];
    __shared__ int    nbroff_s[NPB][KK + 1];
    __shared__ int    work_s;

    const int tid = threadIdx.x;

    // ---- real XCD id (wave-uniform; m09-verified readable on gfx950) ----
    int xcc;
    asm volatile("s_getreg_b32 %0, hwreg(HW_REG_XCC_ID)" : "=s"(xcc));
    xcc &= 7;

    // ---- pop one macro-chunk of OUR XCD's group (tid 0) ----
    if (tid == 0) {
        int gg  = xcc;
        int idx = atomicAdd(&ctr[gg], 1);          // fast path: own group
        if (idx >= CAP) {                          // own group exhausted
            idx = -1;
            for (int a = 1; a < 8 && idx < 0; a++) {
                int g2  = (xcc + a) & 7;
                int old = atomicAdd(&ctr[g2], 0);  // read
                while (old < CAP) {
                    int prev = atomicCAS(&ctr[g2], old, old + 1);
                    if (prev == old) { idx = old; gg = g2; break; }
                    old = prev;
                }
            }
            if (idx < 0) idx = 0;  // unreachable (pigeonhole); dup work is idempotent
        }
        work_s = gg * CAP + idx;
    }

    // ---- stage loop-invariant tensors while tid0 pops ----
    for (int i = tid; i < OO * WTS; i += 192) {
        int o = i / WTS, col = i - o * WTS;
        if (col < TH) Wt_s[i] = W[col * OO + o];
    }
    if (tid < OO) bias_s[tid] = bias[tid];
    __syncthreads();

    const int g      = work_s / CAP;
    const int chunk5 = work_s - g * CAP;
    const char* xgb  = (const char*)xT2 + (size_t)g * (NN * JJ * sizeof(float4));

    for (int q = 0; q < CPB; q++) {
        const int n0 = (chunk5 * CPB + q) * NPB;

        // ---- stage per-chunk: neighbor offsets + gaussian head-weights ----
        if (tid < NPB * KK) {
            int nl = tid >> 4, k = tid & 15;
            nbroff_s[nl][k] = nbrs[(n0 + nl) * KK + k] * (JJ * (int)sizeof(float4));
            float d = dists[(n0 + nl) * KK + k];
            float p = expf(-(d * d) * (1.0f / 144.0f));   // head h uses p^(h+1)
            float4 wv;
            wv.x = p; wv.y = p * p; wv.z = wv.y * p; wv.w = wv.y * wv.y;
            w4_s[nl][k] = wv;
        }
        __syncthreads();

        // ---- phase A: gather (384 B rows) + head-weighted aggregate ----
        {
            const int nl  = tid / JJ;            // 0..7
            const int j   = tid - nl * JJ;       // 0..23
            const int b_l = j / Tin;             // 0..1
            const int t   = j - b_l * Tin;       // 0..11
            const unsigned j16 = (unsigned)j * 16u;

            f2 a0l = {0,0}, a0h = {0,0}, a1l = {0,0}, a1h = {0,0};
            f2 a2l = {0,0}, a2h = {0,0}, a3l = {0,0}, a3h = {0,0};
            #pragma unroll
            for (int k = 0; k < KK; k++) {
                unsigned off = (unsigned)nbroff_s[nl][k] + j16;
                float4 xv = *(const float4*)(xgb + off);
                f2 xl = {xv.x, xv.y}, xh = {xv.z, xv.w};
                float4 wv = w4_s[nl][k];
                f2 w0 = {wv.x, wv.x}, w1 = {wv.y, wv.y};
                f2 w2 = {wv.z, wv.z}, w3 = {wv.w, wv.w};
                a0l += w0 * xl; a0h += w0 * xh;
                a1l += w1 * xl; a1h += w1 * xh;
                a2l += w2 * xl; a2h += w2 * xh;
                a3l += w3 * xl; a3h += w3 * xh;
            }
            const int base = nl * FSN2 + b_l * FSB2 + t;    // + h*12
            feat[base +  0] = float4{a0l.x, a0l.y, a0h.x, a0h.y};
            feat[base + 12] = float4{a1l.x, a1l.y, a1h.x, a1h.y};
            feat[base + 24] = float4{a2l.x, a2l.y, a2h.x, a2h.y};
            feat[base + 36] = float4{a3l.x, a3l.y, a3h.x, a3h.y};
        }
        __syncthreads();

        // ---- phase B: (48 -> 12) GEMM, 1 wave, 3 outputs/thread ----
        if (tid < 64) {
            const int nl   = tid & 7;
            const int rest = tid >> 3;
            const int b_l  = rest & 1;
            const int o3   = rest >> 1;
            const int o0   = 3 * o3;

            float4 acc[3];
            #pragma unroll
            for (int i = 0; i < 3; i++) {
                float bz = bias_s[o0 + i];
                acc[i] = float4{bz, bz, bz, bz};
            }
            const int fb = nl * FSN2 + b_l * FSB2;
            #pragma unroll
            for (int t = 0; t < Tin; t++) {
                float4 f0 = feat[fb + t];
                float4 f1 = feat[fb + 12 + t];
                float4 fq = feat[fb + 24 + t];
                float4 f3 = feat[fb + 36 + t];
                f2 f0l = {f0.x, f0.y}, f0h = {f0.z, f0.w};
                f2 f1l = {f1.x, f1.y}, f1h = {f1.z, f1.w};
                f2 f2l = {fq.x, fq.y}, f2h = {fq.z, fq.w};
                f2 f3l = {f3.x, f3.y}, f3h = {f3.z, f3.w};
                #pragma unroll
                for (int i = 0; i < 3; i++) {
                    const float4 wq = *(const float4*)&Wt_s[(o0 + i) * WTS + t * 4];
                    f2 al = {acc[i].x, acc[i].y}, ah = {acc[i].z, acc[i].w};
                    f2 wx = {wq.x, wq.x}, wy = {wq.y, wq.y};
                    f2 wz = {wq.z, wq.z}, ww = {wq.w, wq.w};
                    al += wx * f0l; ah += wx * f0h;
                    al += wy * f1l; ah += wy * f1h;
                    al += wz * f2l; ah += wz * f2h;
                    al += ww * f3l; ah += ww * f3h;
                    acc[i] = float4{al.x, al.y, ah.x, ah.y};
                }
            }
            const int b = g * 2 + b_l;
            #pragma unroll
            for (int i = 0; i < 3; i++) {
                int o = o0 + i;
                float4 y = acc[i];
                y.x = fmaxf(y.x, 0.0f); y.y = fmaxf(y.y, 0.0f);
                y.z = fmaxf(y.z, 0.0f); y.w = fmaxf(y.w, 0.0f);
                nt_store4(y, &out4[(size_t)(b * Ttot + Tin + o) * NN + n0 + nl]);
            }
        }
        __syncthreads();   // protect feat/w4/nbroff before next chunk's staging
    }
}

extern "C" void kernel_launch(void* const* d_in, const int* in_sizes, int n_in,
                              void* d_out, int out_size, void* d_ws, size_t ws_size,
                              hipStream_t stream) {
    const float* x     = (const float*)d_in[0];
    const float* dists = (const float*)d_in[1];
    const float* W     = (const float*)d_in[2];
    const float* bias  = (const float*)d_in[3];
    const int*   nbrs  = (const int*)d_in[4];
    float4* out4 = (float4*)d_out;
    float4* xT2  = (float4*)d_ws;     // G*NN*JJ*16 B = 15,360,000 B
    int*    ctr  = (int*)((char*)d_ws + 15360000);   // 8 work counters

    hipLaunchKernelGGL(transpose_concat_kernel, dim3(K1_TILES * G), dim3(256), 0,
                       stream, (const float4*)x, xT2, out4, ctr);

    hipLaunchKernelGGL(gnn_main_kernel, dim3(G * CAP), dim3(192), 0, stream,
                       (const float4*)xT2, dists, W, bias, nbrs, out4, ctr);
}